// Round 10
// baseline (2381.049 us; speedup 1.0000x reference)
//
#include <hip/hip_runtime.h>

#define T_STEPS 1024
#define HSZ     64
#define OSZ     128

typedef float4 F4;

__device__ __forceinline__ float fast_rcp(float x) { return __builtin_amdgcn_rcpf(x); }
__device__ __forceinline__ float tanh_fast(float x) {
    float e = __expf(2.0f * x);
    return fmaf(-2.0f, fast_rcp(e + 1.0f), 1.0f);
}

// gate butterfly: gates of unit j sit in lanes 4j..4j+3 (gt = lane&3)
#define GATE_SELECT(act, gt, iv, fv, gv, ov) \
    float q1 = __shfl_xor((act), 1); \
    float q2 = __shfl_xor((act), 2); \
    float q3 = __shfl_xor((act), 3); \
    const bool b0 = (gt) & 1, b1 = (gt) & 2; \
    float iv = b1 ? (b0 ? q3 : q2) : (b0 ? q1 : (act)); \
    float fv = b1 ? (b0 ? q2 : q3) : (b0 ? (act) : q1); \
    float gv = b1 ? (b0 ? q1 : (act)) : (b0 ? q3 : q2); \
    float ov = b1 ? (b0 ? (act) : q1) : (b0 ? q2 : q3);

struct WHH { F4 w[16]; };   // statically-indexed only (full unroll) -> registers

__device__ __forceinline__ WHH load_whh(const F4* base) {
    WHH W;
    #pragma unroll
    for (int k = 0; k < 16; ++k) W.w[k] = base[k];
    return W;
}

// chunk proj, K=128: xg[s][g] = bias[g] + dot(x[s][:], w_ih[g][:]) for s in [0,64)
// w_ih slices re-loaded per kb (fresh 8 VGPRs) -> no large live weight set.
__device__ __forceinline__ void proj128(const F4* wih4 /*row base, 32 F4*/, const F4* xb4,
                                        float* xgb, int u, float gbias) {
    #pragma unroll 1
    for (int pass = 0; pass < 2; ++pass) {
        const int s0 = pass * 32;
        float acc[32];
        #pragma unroll
        for (int s = 0; s < 32; ++s) acc[s] = gbias;
        #pragma unroll 4
        for (int kb = 0; kb < 16; ++kb) {
            F4 w0 = wih4[kb * 2], w1 = wih4[kb * 2 + 1];
            #pragma unroll
            for (int s = 0; s < 32; ++s) {
                F4 x0 = xb4[(s0 + s) * 32 + kb * 2];      // wave-uniform broadcast
                F4 x1 = xb4[(s0 + s) * 32 + kb * 2 + 1];
                acc[s] = fmaf(x0.x, w0.x, acc[s]); acc[s] = fmaf(x0.y, w0.y, acc[s]);
                acc[s] = fmaf(x0.z, w0.z, acc[s]); acc[s] = fmaf(x0.w, w0.w, acc[s]);
                acc[s] = fmaf(x1.x, w1.x, acc[s]); acc[s] = fmaf(x1.y, w1.y, acc[s]);
                acc[s] = fmaf(x1.z, w1.z, acc[s]); acc[s] = fmaf(x1.w, w1.w, acc[s]);
            }
        }
        #pragma unroll
        for (int s = 0; s < 32; ++s) xgb[(s0 + s) * 256 + u] = acc[s];
    }
}

// chunk proj, K=64
__device__ __forceinline__ void proj64(const F4* wih4 /*row base, 16 F4*/, const F4* xb4,
                                       float* xgb, int u, float gbias) {
    #pragma unroll 1
    for (int pass = 0; pass < 2; ++pass) {
        const int s0 = pass * 32;
        float acc[32];
        #pragma unroll
        for (int s = 0; s < 32; ++s) acc[s] = gbias;
        #pragma unroll 4
        for (int kb = 0; kb < 8; ++kb) {
            F4 w0 = wih4[kb * 2], w1 = wih4[kb * 2 + 1];
            #pragma unroll
            for (int s = 0; s < 32; ++s) {
                F4 x0 = xb4[(s0 + s) * 16 + kb * 2];
                F4 x1 = xb4[(s0 + s) * 16 + kb * 2 + 1];
                acc[s] = fmaf(x0.x, w0.x, acc[s]); acc[s] = fmaf(x0.y, w0.y, acc[s]);
                acc[s] = fmaf(x0.z, w0.z, acc[s]); acc[s] = fmaf(x0.w, w0.w, acc[s]);
                acc[s] = fmaf(x1.x, w1.x, acc[s]); acc[s] = fmaf(x1.y, w1.y, acc[s]);
                acc[s] = fmaf(x1.z, w1.z, acc[s]); acc[s] = fmaf(x1.w, w1.w, acc[s]);
            }
        }
        #pragma unroll
        for (int s = 0; s < 32; ++s) xgb[(s0 + s) * 256 + u] = acc[s];
    }
}

// 64 lean LSTM steps; xg preactivations from LDS; w_hh in registers
__device__ __forceinline__ void scan_chunk(const WHH& W, const float* xgb, float (*hbuf)[HSZ],
                                           float* obuf, int tglob0, int u, int j, int gt,
                                           float am, float aa, float ab, float& c, float& h) {
    #pragma unroll 1
    for (int tc = 0; tc < 64; ++tc) {
        const int p = (tglob0 + tc) & 1;
        const F4* hv = reinterpret_cast<const F4*>(hbuf[p]);
        float a0 = 0.f, a1 = 0.f, a2 = 0.f, a3 = 0.f;
        #pragma unroll
        for (int k = 0; k < 16; ++k) {
            F4 v = hv[k];
            a0 = fmaf(v.x, W.w[k].x, a0); a1 = fmaf(v.y, W.w[k].y, a1);
            a2 = fmaf(v.z, W.w[k].z, a2); a3 = fmaf(v.w, W.w[k].w, a3);
        }
        float pre = xgb[tc * 256 + gt * HSZ + j] + (a0 + a1) + (a2 + a3);
        float act = fmaf(aa, fast_rcp(1.0f + __expf(am * pre)), ab);
        GATE_SELECT(act, gt, iv, fv, gv, ov)
        c = fmaf(fv, c, iv * gv);
        h = ov * tanh_fast(c);
        if (gt == 0) { hbuf[p ^ 1][j] = h; obuf[tc * HSZ + j] = h; }
        __syncthreads();
    }
}

// ===================== Layer 0 =====================
extern "C" __global__ void __launch_bounds__(256)
lstm_l0(const float* __restrict__ x,      // [B][T][128]
        const float* __restrict__ h0, const float* __restrict__ c0,
        const float* __restrict__ w_ih,   // [256][128]
        const float* __restrict__ w_hh,   // [256][64]
        const float* __restrict__ b_ih, const float* __restrict__ b_hh,
        float* __restrict__ out0,         // [B][T][64] (ws)
        float* __restrict__ hn, float* __restrict__ cn)
{
    const int u = threadIdx.x, b = blockIdx.x;
    const int j = u >> 2, gt = u & 3;

    __shared__ __align__(16) float xbuf[64 * 128];   // 32 KB: x chunk
    __shared__ __align__(16) float xgb[64 * 256];    // 64 KB: preactivations
    __shared__ __align__(16) float obuf[64 * HSZ];   // 16 KB: h outputs
    __shared__ __align__(16) float hbuf[2][HSZ];

    const float gbias = b_ih[u] + b_hh[u];
    const float am = (gt == 2) ? -2.0f : -1.0f;
    const float aa = (gt == 2) ?  2.0f :  1.0f;
    const float ab = (gt == 2) ? -1.0f :  0.0f;

    const F4* wih4 = reinterpret_cast<const F4*>(w_ih) + (size_t)u * 32;
    const F4* whh4 = reinterpret_cast<const F4*>(w_hh) + (size_t)(gt * HSZ + j) * 16;
    const F4* xb4  = reinterpret_cast<const F4*>(xbuf);

    float c = c0[(size_t)b * HSZ + j];
    float h = 0.f;
    if (gt == 0) hbuf[0][j] = h0[(size_t)b * HSZ + j];

    {   // stage chunk 0
        const F4* src = reinterpret_cast<const F4*>(x + (size_t)b * T_STEPS * 128);
        F4* dst = reinterpret_cast<F4*>(xbuf);
        #pragma unroll
        for (int k = 0; k < 8; ++k) dst[u + 256 * k] = src[u + 256 * k];
    }
    __syncthreads();
    proj128(wih4, xb4, xgb, u, gbias);       // xg for chunk 0
    __syncthreads();
    WHH W = load_whh(whh4);

    #pragma unroll 1
    for (int ch = 0; ch < 16; ++ch) {
        if (ch < 15) {   // stage next chunk's x (xbuf already consumed by last proj)
            const F4* src = reinterpret_cast<const F4*>(x + ((size_t)b * T_STEPS + (ch + 1) * 64) * 128);
            F4* dst = reinterpret_cast<F4*>(xbuf);
            #pragma unroll
            for (int k = 0; k < 8; ++k) dst[u + 256 * k] = src[u + 256 * k];
        }
        __syncthreads();

        scan_chunk(W, xgb, hbuf, obuf, ch * 64, u, j, gt, am, aa, ab, c, h);

        {   // flush h chunk (coalesced)
            const F4* s4 = reinterpret_cast<const F4*>(obuf);
            F4* dst = reinterpret_cast<F4*>(out0 + ((size_t)b * T_STEPS + ch * 64) * HSZ);
            #pragma unroll
            for (int k = 0; k < 4; ++k) dst[u + 256 * k] = s4[u + 256 * k];
        }
        if (ch < 15) {
            proj128(wih4, xb4, xgb, u, gbias);   // xg for chunk ch+1 (clobbers regs)
            W = load_whh(whh4);                  // cheap per-chunk reload
        }
        __syncthreads();   // protect xbuf for next stage + xgb visibility
    }

    if (gt == 0) {
        hn[(size_t)b * HSZ + j] = h;
        cn[(size_t)b * HSZ + j] = c;
    }
}

// ===================== Layer 1 + FC =====================
extern "C" __global__ void __launch_bounds__(256)
lstm_l1(const float* __restrict__ in0,    // [B][T][64] (= out0)
        const float* __restrict__ h0, const float* __restrict__ c0,
        const float* __restrict__ w_ih,   // [256][64]
        const float* __restrict__ w_hh,   // [256][64]
        const float* __restrict__ b_ih, const float* __restrict__ b_hh,
        const float* __restrict__ w_fc,   // [128][64]
        const float* __restrict__ b_fc,   // [128]
        float* __restrict__ logits,       // [B*T][128]
        float* __restrict__ hn, float* __restrict__ cn)
{
    const int u = threadIdx.x, b = blockIdx.x;
    const int j = u >> 2, gt = u & 3;
    const int o = u & 127, th = u >> 7;   // FC: output o, t-half th

    __shared__ __align__(16) float xbuf[64 * HSZ];   // 16 KB: layer-0 h chunk
    __shared__ __align__(16) float xgb[64 * 256];    // 64 KB
    __shared__ __align__(16) float obuf[64 * HSZ];   // 16 KB: layer-1 h chunk
    __shared__ __align__(16) float hbuf[2][HSZ];

    const float gbias = b_ih[u] + b_hh[u];
    const float bfc   = b_fc[o];
    const float am = (gt == 2) ? -2.0f : -1.0f;
    const float aa = (gt == 2) ?  2.0f :  1.0f;
    const float ab = (gt == 2) ? -1.0f :  0.0f;

    const F4* wih4 = reinterpret_cast<const F4*>(w_ih) + (size_t)u * 16;
    const F4* whh4 = reinterpret_cast<const F4*>(w_hh) + (size_t)(gt * HSZ + j) * 16;
    const F4* wfc4 = reinterpret_cast<const F4*>(w_fc) + (size_t)o * 16;
    const F4* xb4  = reinterpret_cast<const F4*>(xbuf);
    const F4* ob4  = reinterpret_cast<const F4*>(obuf);

    float c = c0[(size_t)b * HSZ + j];
    float h = 0.f;
    if (gt == 0) hbuf[0][j] = h0[(size_t)b * HSZ + j];

    {   // stage chunk 0 of layer-0 output
        const F4* src = reinterpret_cast<const F4*>(in0 + (size_t)b * T_STEPS * HSZ);
        F4* dst = reinterpret_cast<F4*>(xbuf);
        #pragma unroll
        for (int k = 0; k < 4; ++k) dst[u + 256 * k] = src[u + 256 * k];
    }
    __syncthreads();
    proj64(wih4, xb4, xgb, u, gbias);
    __syncthreads();
    WHH W = load_whh(whh4);

    #pragma unroll 1
    for (int ch = 0; ch < 16; ++ch) {
        if (ch < 15) {
            const F4* src = reinterpret_cast<const F4*>(in0 + ((size_t)b * T_STEPS + (ch + 1) * 64) * HSZ);
            F4* dst = reinterpret_cast<F4*>(xbuf);
            #pragma unroll
            for (int k = 0; k < 4; ++k) dst[u + 256 * k] = src[u + 256 * k];
        }
        __syncthreads();

        scan_chunk(W, xgb, hbuf, obuf, ch * 64, u, j, gt, am, aa, ab, c, h);

        {   // FC for this chunk: thread (o, th) covers 32 steps; fc weights fresh per kb
            float fac[32];
            #pragma unroll
            for (int s = 0; s < 32; ++s) fac[s] = bfc;
            #pragma unroll 4
            for (int kb = 0; kb < 8; ++kb) {
                F4 f0 = wfc4[kb * 2], f1 = wfc4[kb * 2 + 1];
                #pragma unroll
                for (int s = 0; s < 32; ++s) {
                    F4 h0v = ob4[(th * 32 + s) * 16 + kb * 2];     // wave-uniform
                    F4 h1v = ob4[(th * 32 + s) * 16 + kb * 2 + 1];
                    fac[s] = fmaf(h0v.x, f0.x, fac[s]); fac[s] = fmaf(h0v.y, f0.y, fac[s]);
                    fac[s] = fmaf(h0v.z, f0.z, fac[s]); fac[s] = fmaf(h0v.w, f0.w, fac[s]);
                    fac[s] = fmaf(h1v.x, f1.x, fac[s]); fac[s] = fmaf(h1v.y, f1.y, fac[s]);
                    fac[s] = fmaf(h1v.z, f1.z, fac[s]); fac[s] = fmaf(h1v.w, f1.w, fac[s]);
                }
            }
            #pragma unroll
            for (int s = 0; s < 32; ++s)
                logits[((size_t)b * T_STEPS + ch * 64 + th * 32 + s) * OSZ + o] = fac[s];
        }

        if (ch < 15) {
            proj64(wih4, xb4, xgb, u, gbias);
            W = load_whh(whh4);
        }
        __syncthreads();
    }

    if (gt == 0) {
        hn[(size_t)b * HSZ + j] = h;
        cn[(size_t)b * HSZ + j] = c;
    }
}

extern "C" void kernel_launch(void* const* d_in, const int* in_sizes, int n_in,
                              void* d_out, int out_size, void* d_ws, size_t ws_size,
                              hipStream_t stream) {
    const float* x     = (const float*)d_in[0];
    const float* h0    = (const float*)d_in[1];
    const float* c0    = (const float*)d_in[2];
    const float* w_ih0 = (const float*)d_in[3];
    const float* w_hh0 = (const float*)d_in[4];
    const float* b_ih0 = (const float*)d_in[5];
    const float* b_hh0 = (const float*)d_in[6];
    const float* w_ih1 = (const float*)d_in[7];
    const float* w_hh1 = (const float*)d_in[8];
    const float* b_ih1 = (const float*)d_in[9];
    const float* b_hh1 = (const float*)d_in[10];
    const float* w_fc  = (const float*)d_in[11];
    const float* b_fc  = (const float*)d_in[12];

    float* out = (float*)d_out;
    const size_t n_logits = (size_t)256 * T_STEPS * OSZ;
    const size_t n_state  = (size_t)256 * HSZ;
    float* logits = out;
    float* hn     = out + n_logits;
    float* cn     = hn + 2 * n_state;

    float* out0 = (float*)d_ws;   // [256][1024][64] = 67 MB

    lstm_l0<<<256, 256, 0, stream>>>(
        x, h0, c0, w_ih0, w_hh0, b_ih0, b_hh0, out0, hn, cn);

    lstm_l1<<<256, 256, 0, stream>>>(
        out0, h0 + n_state, c0 + n_state,
        w_ih1, w_hh1, b_ih1, b_hh1, w_fc, b_fc,
        logits, hn + n_state, cn + n_state);
}